// Round 9
// baseline (551.665 us; speedup 1.0000x reference)
//
#include <hip/hip_runtime.h>
#include <hip/hip_bf16.h>

#define D_MODEL 1024
#define NUM_HEADS 16
#define DK 64
#define BATCH 4
#define SEQ 2048

typedef __hip_bfloat16 bf16;
typedef __attribute__((ext_vector_type(8))) short bf16x8;  // MFMA A/B frag (4 VGPRs)
typedef __attribute__((ext_vector_type(4))) short bf16x4;
typedef __attribute__((ext_vector_type(4))) float f32x4;   // MFMA C/D frag

typedef __attribute__((address_space(1))) const unsigned int gu32;
typedef __attribute__((address_space(3))) unsigned int lu32;

// Q is pre-scaled by this in the projection GEMM so attn's softmax is exp2(a).
#define QSCALE (0.125f * 1.44269504089f)   // 1/sqrt(64) * log2(e)

// Direct HBM->LDS DMA, 16 B per lane. LDS dst must be wave-uniform base +
// lane*16 (m97/m104). Per-lane global address is free -> use it to realize
// an XOR-swizzled LDS layout for conflict-free frag reads.
__device__ __forceinline__ void gll16(const bf16* g, bf16* l) {
    __builtin_amdgcn_global_load_lds((gu32*)g, (lu32*)l, 16, 0, 0);
}

// Swizzled frag read from a 64-elem-stride tile: element (row, h*32+quad*8+j)
// lives at row*64 + ((h*4+quad)^(row&7))*8 + j.
__device__ __forceinline__ bf16x8 frag_ld(const bf16* lds, int row, int h, int quad) {
    return *(const bf16x8*)(lds + row * 64 + (((h << 2) + quad) ^ (row & 7)) * 8);
}

// Swizzled frag read from a 32-elem-stride tile (BK=32): element
// (row, quad*8+j) lives at row*32 + (quad^(row&3))*8 + j.
__device__ __forceinline__ bf16x8 frag_ld32(const bf16* lds, int row, int quad) {
    return *(const bf16x8*)(lds + row * 32 + ((quad ^ (row & 3))) * 8);
}

// ---------------------------------------------------------------------------
// Pre-convert x and the 4 weight matrices to bf16 (one memory-bound pass).
// ---------------------------------------------------------------------------
__global__ __launch_bounds__(256)
void cvt_bf16(const float* __restrict__ x,  const float* __restrict__ Wq,
              const float* __restrict__ Wk, const float* __restrict__ Wv,
              const float* __restrict__ Wo, bf16* __restrict__ xb,
              bf16* __restrict__ Wb)
{
    size_t v = (size_t)blockIdx.x * 256 + threadIdx.x;   // vec4 id (total 3145728)
    size_t e = v * 4;
    const float* src; bf16* dst; size_t off;
    if (e < 8388608) { src = x; dst = xb; off = e; }
    else {
        size_t r = e - 8388608;
        int w = (int)(r >> 20);
        off = r & 1048575;
        src = (w == 0) ? Wq : (w == 1) ? Wk : (w == 2) ? Wv : Wo;
        dst = Wb + ((size_t)w << 20);
    }
    float4 f = *(const float4*)(src + off);
    bf16 o[4] = {__float2bfloat16(f.x), __float2bfloat16(f.y),
                 __float2bfloat16(f.z), __float2bfloat16(f.w)};
    *(bf16x4*)(dst + off) = *(const bf16x4*)o;
}

// ---------------------------------------------------------------------------
// QKV projection GEMM v5: occupancy-first. BM=BN=256, BK=32, 512 threads =
// 8 waves (2M x 4N), per-wave 128x64 (8x4 frags), 32 MFMA : 12 ds_read_b128
// per wave per K-tile. LDS = 2 dbufs x (A 16KB + B 16KB) = 64 KB ->
// 2 blocks/CU: cross-block wave overlap hides the per-tile barrier drain
// (m114 mechanism; the 1-block/CU 128KB variants all pinned at ~22% MfmaUtil
// regardless of schedule -- R4-R6). Simple proven loop (attn-v3 style):
// prefetch next buf -> compute -> one syncthreads.
// W = concat[Wq;Wk;Wv] contiguous in Wb. grid (12,32) = 384 blocks.
// ---------------------------------------------------------------------------
__global__ __launch_bounds__(512, 4)
void gemm_qkv(const bf16* __restrict__ A, const bf16* __restrict__ W,
              const float* __restrict__ bqv, const float* __restrict__ bkv,
              const float* __restrict__ bvv,
              bf16* __restrict__ Q, bf16* __restrict__ Kt, bf16* __restrict__ Vtr)
{
    // buf d: A tile (256x32) at d*16384, B tile (256x32) at d*16384+8192
    __shared__ bf16 lds[32768];          // 64 KB -> 2 blocks/CU

    const int t = threadIdx.x;
    const int wave = t >> 6, lane = t & 63;
    const int quad = lane >> 4, l16 = lane & 15;
    const int wm = wave >> 2, wn = wave & 3;     // 2M x 4N wave grid

    const int colb = blockIdx.x;
    const int rowBase = blockIdx.y * 256;

    const bf16* Ablk = A + (size_t)rowBase * 1024;
    const bf16* Bblk = W + (size_t)colb * 256 * 1024;

    // Stage one K-tile (A+B, 32 KB): 4 gll16/thread. Chunk idx 0..1023 per
    // matrix: row = idx>>2, col-chunk cl = idx&3, global chunk cg = cl^(row&3).
    auto stage = [&](int d, int k0) {
        bf16* buf = (bf16*)lds + d * 16384;
        #pragma unroll
        for (int p = 0; p < 2; ++p) {
            int idx = t + p * 512;
            int row = idx >> 2, cg = (idx & 3) ^ (row & 3);
            gll16(Ablk + (size_t)row * 1024 + k0 + cg * 8, buf + idx * 8);
            gll16(Bblk + (size_t)row * 1024 + k0 + cg * 8, buf + 8192 + idx * 8);
        }
    };

    f32x4 acc[8][4];
    #pragma unroll
    for (int mf = 0; mf < 8; ++mf)
        #pragma unroll
        for (int nf = 0; nf < 4; ++nf) acc[mf][nf] = (f32x4){0.f, 0.f, 0.f, 0.f};

    stage(0, 0);
    __syncthreads();

    for (int kt = 0; kt < 32; ++kt) {
        const int cur = kt & 1;
        if (kt + 1 < 32) stage(cur ^ 1, (kt + 1) * 32);   // prefetch next tile

        const bf16* As = (const bf16*)lds + cur * 16384;
        const bf16* Bs = As + 8192;

        bf16x8 bfr[4];
        #pragma unroll
        for (int nf = 0; nf < 4; ++nf)
            bfr[nf] = frag_ld32(Bs, wn * 64 + nf * 16 + l16, quad);

        __builtin_amdgcn_s_setprio(1);
        #pragma unroll
        for (int mf = 0; mf < 8; ++mf) {
            bf16x8 af = frag_ld32(As, wm * 128 + mf * 16 + l16, quad);
            #pragma unroll
            for (int nf = 0; nf < 4; ++nf)
                acc[mf][nf] = __builtin_amdgcn_mfma_f32_16x16x32_bf16(
                    af, bfr[nf], acc[mf][nf], 0, 0, 0);
        }
        __builtin_amdgcn_s_setprio(0);

        // one barrier per tile: drains prefetch DMA + protects buf cur^1
        __syncthreads();
    }

    // ---- epilogue: scatter Q (pre-scaled), Kt, Vtr ----
    {
        const int proj = colb >> 2;
        const float* bias = proj == 0 ? bqv : (proj == 1 ? bkv : bvv);
        const int cb = (colb & 3) * 256;
        float bias4[4];
        #pragma unroll
        for (int nf = 0; nf < 4; ++nf)
            bias4[nf] = bias[cb + wn * 64 + nf * 16 + l16];
        const float oscale = proj == 0 ? QSCALE : 1.0f;
        #pragma unroll
        for (int mf = 0; mf < 8; ++mf)
            #pragma unroll
            for (int rr = 0; rr < 4; ++rr) {
                int r = rowBase + wm * 128 + mf * 16 + quad * 4 + rr;
                int b_ = r >> 11, s_ = r & 2047;
                #pragma unroll
                for (int nf = 0; nf < 4; ++nf) {
                    int c = cb + wn * 64 + nf * 16 + l16;
                    float v = (acc[mf][nf][rr] + bias4[nf]) * oscale;
                    int h_ = c >> 6, d_ = c & 63;
                    size_t bh = (size_t)(b_ * NUM_HEADS + h_);
                    if (proj == 2)
                        Vtr[(bh * DK + d_) * SEQ + s_] = __float2bfloat16(v);
                    else {
                        bf16* dst = proj == 0 ? Q : Kt;
                        dst[(bh * SEQ + s_) * DK + d_] = __float2bfloat16(v);
                    }
                }
            }
    }
}

// ---------------------------------------------------------------------------
// GEMM tile staging via global_load_lds: 128 rows x 64 k (16 KB), unpadded
// stride 64, chunk-XOR swizzle. Each thread DMAs 4 x 16 B. (256 threads)
// ---------------------------------------------------------------------------
__device__ __forceinline__ void stage_gll128(const bf16* __restrict__ src,
                                             bf16* lds, int t, int k0)
{
    #pragma unroll
    for (int p = 0; p < 4; ++p) {
        int idx = t + p * 256;            // chunk id 0..1023
        int row = idx >> 3, cl = idx & 7;
        int cg = cl ^ (row & 7);
        gll16(src + (size_t)row * 1024 + k0 + cg * 8, lds + idx * 8);
    }
}

// ---------------------------------------------------------------------------
// Output projection (known-good m97-style 128x128, BK=64):
// out(f32) = ctx @ Wo^T + bo. grid (8,64) = 512 blocks = 2.0 exact rounds.
// ---------------------------------------------------------------------------
__global__ __launch_bounds__(256)
void gemm_out(const bf16* __restrict__ ctx, const bf16* __restrict__ Wb,
              const float* __restrict__ bo, float* __restrict__ out)
{
    __shared__ bf16 As[128 * 64];
    __shared__ bf16 Bs[128 * 64];
    const int t = threadIdx.x;
    const int wave = t >> 6, lane = t & 63;
    const int quad = lane >> 4, l16 = lane & 15;
    const int wr = wave >> 1, wc = wave & 1;
    const int colBase = blockIdx.x * 128;
    const int rowBase = blockIdx.y * 128;

    const bf16* Ablk = ctx + (size_t)rowBase * 1024;
    const bf16* Bblk = Wb + ((size_t)3 << 20) + (size_t)colBase * 1024;

    f32x4 acc[4][4];
    #pragma unroll
    for (int i = 0; i < 4; ++i)
        #pragma unroll
        for (int j = 0; j < 4; ++j) acc[i][j] = (f32x4){0.f, 0.f, 0.f, 0.f};

    for (int k0 = 0; k0 < 1024; k0 += 64) {
        stage_gll128(Ablk, As, t, k0);
        stage_gll128(Bblk, Bs, t, k0);
        __syncthreads();
        #pragma unroll
        for (int h = 0; h < 2; ++h) {
            bf16x8 af[4], bfr[4];
            #pragma unroll
            for (int i = 0; i < 4; ++i)
                af[i] = frag_ld(As, wr * 64 + i * 16 + l16, h, quad);
            #pragma unroll
            for (int j = 0; j < 4; ++j)
                bfr[j] = frag_ld(Bs, wc * 64 + j * 16 + l16, h, quad);
            #pragma unroll
            for (int i = 0; i < 4; ++i)
                #pragma unroll
                for (int j = 0; j < 4; ++j)
                    acc[i][j] = __builtin_amdgcn_mfma_f32_16x16x32_bf16(af[i], bfr[j],
                                                                        acc[i][j], 0, 0, 0);
        }
        __syncthreads();
    }

    float bias4[4];
    #pragma unroll
    for (int j = 0; j < 4; ++j)
        bias4[j] = bo[colBase + wc * 64 + j * 16 + l16];

    #pragma unroll
    for (int i = 0; i < 4; ++i)
        #pragma unroll
        for (int rr = 0; rr < 4; ++rr) {
            int r = rowBase + wr * 64 + i * 16 + quad * 4 + rr;
            #pragma unroll
            for (int j = 0; j < 4; ++j) {
                int c = colBase + wc * 64 + j * 16 + l16;
                out[(size_t)r * 1024 + c] = acc[i][j][rr] + bias4[j];
            }
        }
}

// ---------------------------------------------------------------------------
// Flash attention v3 (reverted from v4 -- QBLK=256 cut blocks/CU 3->2 and
// doubled the critical path; cross-block overlap was carrying v3):
// 128 q-rows/block (4 waves x 32 rows), double-buffered K/V staging (one
// barrier per 64-key tile), K-frags cached in registers, V-frags shared
// across the two 16-row sub-blocks. Q pre-scaled: p = exp2(a) exact.
// grid = (bh=64, 16): linear id == bh (mod 8) -> all 16 q-blocks of one bh
// colocate on one XCD; per-XCD live K/V set = 8 bh * 0.5 MB = 4 MB = L2.
// qbi = 15 - blockIdx.y: heaviest q-blocks dispatch first (no long tail).
// ---------------------------------------------------------------------------
#define AS 72   // Ps stride only (regular ds ops, 2-way alias = free)

__device__ __forceinline__ void stage_attn(const bf16* __restrict__ Kb,
                                           const bf16* __restrict__ Vb,
                                           int k0, bf16* ks, bf16* vs, int t)
{
    #pragma unroll
    for (int p = 0; p < 2; ++p) {
        int idx = t + p * 256;            // chunk id 0..511
        int row = idx >> 3, cl = idx & 7;
        int cg = cl ^ (row & 7);
        gll16(Kb + (size_t)(k0 + row) * DK + cg * 8, ks + idx * 8);
        gll16(Vb + (size_t)row * SEQ + k0 + cg * 8, vs + idx * 8);
    }
}

__global__ __launch_bounds__(256)
void attn_mfma(const bf16* __restrict__ Q, const bf16* __restrict__ K,
               const bf16* __restrict__ Vt, bf16* __restrict__ ctx)
{
    __shared__ bf16 Ks[2][64 * 64];
    __shared__ bf16 Vs[2][64 * 64];
    __shared__ bf16 Ps[4][2][16 * AS];

    const int t    = threadIdx.x;
    const int wave = t >> 6, lane = t & 63;
    const int quad = lane >> 4, l16 = lane & 15;
    const int bh   = blockIdx.x;              // 0..63 (fast dim -> XCD = bh&7)
    const int qbi  = 15 - blockIdx.y;         // heavy blocks first
    const int b_ = bh >> 4, h_ = bh & 15;

    const bf16* Qb = Q  + (size_t)bh * SEQ * DK;
    const bf16* Kb = K  + (size_t)bh * SEQ * DK;
    const bf16* Vb = Vt + (size_t)bh * DK * SEQ;

    const int qb  = qbi * 128;
    const int ntiles = 2 * qbi + 2;               // 64-key tiles (even)

    // Q fragments for this wave's 32 rows (2 x 16-row frags, 2 k-halves)
    bf16x8 qf[2][2];
    #pragma unroll
    for (int i = 0; i < 2; ++i) {
        const int qrow = qb + wave * 32 + i * 16 + l16;
        qf[i][0] = *(const bf16x8*)(Qb + (size_t)qrow * DK + quad * 8);
        qf[i][1] = *(const bf16x8*)(Qb + (size_t)qrow * DK + 32 + quad * 8);
    }

    f32x4 O[2][4];
    float lsum[2][4];
    #pragma unroll
    for (int i = 0; i < 2; ++i)
        #pragma unroll
        for (int nc = 0; nc < 4; ++nc) {
            O[i][nc] = (f32x4){0.f, 0.f, 0.f, 0.f};
            lsum[i][nc] = 0.f;
        }

    stage_attn(Kb, Vb, 0, Ks[0], Vs[0], t);
    __syncthreads();

    for (int kt = 0; kt < ntiles; ++kt) {
        const int cur = kt & 1;
        const int k0  = kt * 64;
        if (kt + 1 < ntiles)                      // prefetch next tile
            stage_attn(Kb, Vb, k0 + 64, Ks[cur ^ 1], Vs[cur ^ 1], t);

        const bool diag = (kt + 2 >= ntiles);     // last two tiles: mask
        const bool skip = (kt == ntiles - 1) && (wave < 2);  // fully masked

        if (!skip) {
            // cache all K fragments for this tile (reused by both i)
            bf16x8 kf[4][2];
            #pragma unroll
            for (int h = 0; h < 4; ++h) {
                kf[h][0] = frag_ld(Ks[cur], h * 16 + l16, 0, quad);
                kf[h][1] = frag_ld(Ks[cur], h * 16 + l16, 1, quad);
            }

            // ---- S = Q K^T + softmax (Q pre-scaled: p = exp2(a)) ----
            #pragma unroll
            for (int i = 0; i < 2; ++i) {
                const int qrow0i = qb + wave * 32 + i * 16;
                float lacc[4];
                #pragma unroll
                for (int r = 0; r < 4; ++r) lacc[r] = lsum[i][r];
                #pragma unroll
                for (int h = 0; h < 4; ++h) {
                    f32x4 a = (f32x4){0.f, 0.f, 0.f, 0.f};
                    a = __builtin_amdgcn_mfma_f32_16x16x32_bf16(qf[i][0], kf[h][0], a, 0, 0, 0);
                    a = __builtin_amdgcn_mfma_f32_16x16x32_bf16(qf[i][1], kf[h][1], a, 0, 0, 0);
                    #pragma unroll
                    for (int r = 0; r < 4; ++r) {
                        float ss = a[r];
                        if (diag && (k0 + h * 16 + l16 > qrow0i + quad * 4 + r))
                            ss = -1e30f;
                        float p = exp2f(ss);
                        lacc[r] += p;
                        Ps[wave][i][(quad * 4 + r) * AS + h * 16 + l16] =
                            __float2bfloat16(p);
                    }
                }
                #pragma unroll
                for (int r = 0; r < 4; ++r) lsum[i][r] = lacc[r];
            }

            // ---- O += P V : V frags loaded once, shared across both i ----
            bf16x8 pf[2][2];
            #pragma unroll
            for (int i = 0; i < 2; ++i) {
                pf[i][0] = *(const bf16x8*)(&Ps[wave][i][l16 * AS + quad * 8]);
                pf[i][1] = *(const bf16x8*)(&Ps[wave][i][l16 * AS + 32 + quad * 8]);
            }
            __builtin_amdgcn_s_setprio(1);
            #pragma unroll
            for (int nc = 0; nc < 4; ++nc) {
                bf16x8 vf0 = frag_ld(Vs[cur], nc * 16 + l16, 0, quad);
                bf16x8 vf1 = frag_ld(Vs[cur], nc * 16 + l16, 1, quad);
                #pragma unroll
                for (int i = 0; i < 2; ++i) {
                    O[i][nc] = __builtin_amdgcn_mfma_f32_16x16x32_bf16(pf[i][0], vf0, O[i][nc], 0, 0, 0);
                    O[i][nc] = __builtin_amdgcn_mfma_f32_16x16x32_bf16(pf[i][1], vf1, O[i][nc], 0, 0, 0);
                }
            }
            __builtin_amdgcn_s_setprio(0);
        }
        // single barrier per tile: drains the prefetch DMA (vmcnt) and
        // protects the buffer being overwritten next iteration
        __syncthreads();
    }

    // ---- epilogue: reduce l across the 16 column-lanes, write ctx ----
    // (rcp instead of full-precision divides; bf16 output hides the ulp)
    #pragma unroll
    for (int i = 0; i < 2; ++i) {
        float inv[4];
        #pragma unroll
        for (int r = 0; r < 4; ++r) {
            #pragma unroll
            for (int off = 1; off < 16; off <<= 1)
                lsum[i][r] += __shfl_xor(lsum[i][r], off, 64);
            inv[r] = __builtin_amdgcn_rcpf(lsum[i][r]);
        }
        #pragma unroll
        for (int nc = 0; nc < 4; ++nc)
            #pragma unroll
            for (int r = 0; r < 4; ++r) {
                const int row = qb + wave * 32 + i * 16 + quad * 4 + r;
                float v = O[i][nc][r] * inv[r];
                ctx[((size_t)(b_ * SEQ + row)) * D_MODEL + h_ * DK + nc * 16 + l16] =
                    __float2bfloat16(v);
            }
    }
}

extern "C" void kernel_launch(void* const* d_in, const int* in_sizes, int n_in,
                              void* d_out, int out_size, void* d_ws, size_t ws_size,
                              hipStream_t stream) {
    const float* x  = (const float*)d_in[0];
    // d_in[1] = mask (int32) — unused; causal j<=q is exactly equivalent
    const float* Wq = (const float*)d_in[2];
    const float* bq = (const float*)d_in[3];
    const float* Wk = (const float*)d_in[4];
    const float* bk = (const float*)d_in[5];
    const float* Wv = (const float*)d_in[6];
    const float* bv = (const float*)d_in[7];
    const float* Wo = (const float*)d_in[8];
    const float* bo = (const float*)d_in[9];
    float* out = (float*)d_out;

    const size_t per = (size_t)BATCH * NUM_HEADS * SEQ * DK;  // 8388608
    bf16* Q   = (bf16*)d_ws;
    bf16* Kt  = Q  + per;
    bf16* Vtr = Kt + per;              // transposed V: [B,H,DK,S]
    bf16* xb  = Vtr + per;             // x in bf16; dead after gemm_qkv
    bf16* ctx = xb;                    // ctx aliases xb (written by attn)
    bf16* Wb  = xb + per;              // 4 x 1048576 bf16 weights (Wq,Wk,Wv,Wo)

    hipLaunchKernelGGL(cvt_bf16, dim3(12288), dim3(256), 0, stream,
                       x, Wq, Wk, Wv, Wo, xb, Wb);

    hipLaunchKernelGGL(gemm_qkv, dim3(12, 32), dim3(512), 0, stream,
                       xb, Wb, bq, bk, bv, Q, Kt, Vtr);

    hipLaunchKernelGGL(attn_mfma, dim3(64, 16), dim3(256), 0,
                       stream, Q, Kt, Vtr, ctx);

    hipLaunchKernelGGL(gemm_out, dim3(8, 64), dim3(256), 0, stream,
                       ctx, Wb, bo, out);
}

// Round 10
// 289.774 us; speedup vs baseline: 1.9038x; 1.9038x over previous
//
#include <hip/hip_runtime.h>
#include <hip/hip_bf16.h>

#define D_MODEL 1024
#define NUM_HEADS 16
#define DK 64
#define BATCH 4
#define SEQ 2048

typedef __hip_bfloat16 bf16;
typedef __attribute__((ext_vector_type(8))) short bf16x8;  // MFMA A/B frag (4 VGPRs)
typedef __attribute__((ext_vector_type(4))) short bf16x4;
typedef __attribute__((ext_vector_type(4))) float f32x4;   // MFMA C/D frag

typedef __attribute__((address_space(1))) const unsigned int gu32;
typedef __attribute__((address_space(3))) unsigned int lu32;

// Q is pre-scaled by this in the projection GEMM so attn's softmax is exp2(a).
#define QSCALE (0.125f * 1.44269504089f)   // 1/sqrt(64) * log2(e)

#define FENCE asm volatile("" ::: "memory")
#define BAR_OPEN()  do { FENCE; __builtin_amdgcn_s_barrier();              \
    asm volatile("s_waitcnt lgkmcnt(0)" ::: "memory");                     \
    __builtin_amdgcn_sched_barrier(0); } while (0)
#define BAR_CLOSE() do { FENCE; __builtin_amdgcn_s_barrier(); FENCE; } while (0)

// Direct HBM->LDS DMA, 16 B per lane. LDS dst must be wave-uniform base +
// lane*16 (m97/m104). Per-lane global address is free -> use it to realize
// an XOR-swizzled LDS layout (chunk ^= row&7) for conflict-free frag reads.
__device__ __forceinline__ void gll16(const bf16* g, bf16* l) {
    __builtin_amdgcn_global_load_lds((gu32*)g, (lu32*)l, 16, 0, 0);
}

// Swizzled frag read from a 64-elem-stride tile: element (row, h*32+quad*8+j)
// lives at row*64 + ((h*4+quad)^(row&7))*8 + j.
__device__ __forceinline__ bf16x8 frag_ld(const bf16* lds, int row, int h, int quad) {
    return *(const bf16x8*)(lds + row * 64 + (((h << 2) + quad) ^ (row & 7)) * 8);
}

// ---------------------------------------------------------------------------
// Pre-convert x and the 4 weight matrices to bf16 (one memory-bound pass).
// ---------------------------------------------------------------------------
__global__ __launch_bounds__(256)
void cvt_bf16(const float* __restrict__ x,  const float* __restrict__ Wq,
              const float* __restrict__ Wk, const float* __restrict__ Wv,
              const float* __restrict__ Wo, bf16* __restrict__ xb,
              bf16* __restrict__ Wb)
{
    size_t v = (size_t)blockIdx.x * 256 + threadIdx.x;   // vec4 id (total 3145728)
    size_t e = v * 4;
    const float* src; bf16* dst; size_t off;
    if (e < 8388608) { src = x; dst = xb; off = e; }
    else {
        size_t r = e - 8388608;
        int w = (int)(r >> 20);
        off = r & 1048575;
        src = (w == 0) ? Wq : (w == 1) ? Wk : (w == 2) ? Wv : Wo;
        dst = Wb + ((size_t)w << 20);
    }
    float4 f = *(const float4*)(src + off);
    bf16 o[4] = {__float2bfloat16(f.x), __float2bfloat16(f.y),
                 __float2bfloat16(f.z), __float2bfloat16(f.w)};
    *(bf16x4*)(dst + off) = *(const bf16x4*)o;
}

// ---------------------------------------------------------------------------
// 8-phase 256x256 QKV projection GEMM (best measured variant, R6/R7: 92.5 us,
// MfmaUtil ~22% -- schedule-capped on this problem; R9 showed the occupancy
// escape is impossible: 128-VGPR acc forces 1 block/CU at this tile).
// BM=BN=256, BK=64, 512 threads = 8 waves (2M x 4N), per-wave 128x64.
// 128 KB LDS = 2 K-tile dbufs. vmcnt(4)@P3 / vmcnt(8)@P7, never 0 mid-loop.
// W = concat[Wq;Wk;Wv] (contiguous in Wb), grid (12,32).
// ---------------------------------------------------------------------------
__global__ __launch_bounds__(512, 1)
void gemm_qkv(const bf16* __restrict__ A, const bf16* __restrict__ W,
              const float* __restrict__ bqv, const float* __restrict__ bkv,
              const float* __restrict__ bvv,
              bf16* __restrict__ Q, bf16* __restrict__ Kt, bf16* __restrict__ Vtr)
{
    __shared__ bf16 lds[65536];          // 128 KB -> 1 block/CU

    const int t = threadIdx.x;
    const int wave = t >> 6, lane = t & 63;
    const int quad = lane >> 4, l16 = lane & 15;
    const int wm = wave >> 2, wn = wave & 3;     // 2M x 4N wave grid

    const int colb = blockIdx.x;
    const int rowBase = blockIdx.y * 256;

    const bf16* Ablk = A + (size_t)rowBase * 1024;
    const bf16* Bblk = W + (size_t)colb * 256 * 1024;

    auto stageAhalf = [&](int d, int h, int k0) {
        bf16* dst = (bf16*)lds + d * 16384 + h * 8192;
        #pragma unroll
        for (int p = 0; p < 2; ++p) {
            int idx = t + p * 512;               // chunk 0..1023
            int row = idx >> 3, cg = (idx & 7) ^ (row & 7);
            gll16(Ablk + (size_t)(h * 128 + row) * 1024 + k0 + cg * 8, dst + idx * 8);
        }
    };
    auto stageBhalf = [&](int d, int h, int k0) {
        bf16* dst = (bf16*)lds + 32768 + d * 16384 + h * 8192;
        #pragma unroll
        for (int p = 0; p < 2; ++p) {
            int idx = t + p * 512;
            int row = idx >> 3, cg = (idx & 7) ^ (row & 7);
            gll16(Bblk + (size_t)(h * 128 + row) * 1024 + k0 + cg * 8, dst + idx * 8);
        }
    };

    f32x4 acc[8][4];
    #pragma unroll
    for (int mf = 0; mf < 8; ++mf)
        #pragma unroll
        for (int nf = 0; nf < 4; ++nf) acc[mf][nf] = (f32x4){0.f, 0.f, 0.f, 0.f};

    const bf16* Aha = (const bf16*)lds + wm * 8192;              // dbuf0
    const bf16* Ahb = (const bf16*)lds + 16384 + wm * 8192;      // dbuf1
    const bf16* Bha = (const bf16*)lds + 32768 + (wn >> 1) * 8192;
    const bf16* Bhb = (const bf16*)lds + 49152 + (wn >> 1) * 8192;
    const int brow0 = (wn & 1) * 64;

    auto rdA4 = [&](bf16x8 (&f)[4][2], const bf16* Ah, int mh) {
        #pragma unroll
        for (int m4 = 0; m4 < 4; ++m4)
            #pragma unroll
            for (int kk = 0; kk < 2; ++kk)
                f[m4][kk] = frag_ld(Ah, mh * 64 + m4 * 16 + l16, kk, quad);
    };
    auto rdB2 = [&](bf16x8 (&f)[2][2], const bf16* Bh, int nh) {
        #pragma unroll
        for (int n2 = 0; n2 < 2; ++n2)
            #pragma unroll
            for (int kk = 0; kk < 2; ++kk)
                f[n2][kk] = frag_ld(Bh, brow0 + nh * 32 + n2 * 16 + l16, kk, quad);
    };
    auto mfma16 = [&](bf16x8 (&af)[4][2], bf16x8 (&bfr)[2][2], int mh, int nh) {
        __builtin_amdgcn_s_setprio(1);
        #pragma unroll
        for (int kk = 0; kk < 2; ++kk)
            #pragma unroll
            for (int m4 = 0; m4 < 4; ++m4)
                #pragma unroll
                for (int n2 = 0; n2 < 2; ++n2)
                    acc[mh * 4 + m4][nh * 2 + n2] =
                        __builtin_amdgcn_mfma_f32_16x16x32_bf16(
                            af[m4][kk], bfr[n2][kk], acc[mh * 4 + m4][nh * 2 + n2],
                            0, 0, 0);
        __builtin_amdgcn_s_setprio(0);
    };

    // ---- prologue ----
    stageBhalf(0, 0, 0);  stageBhalf(0, 1, 0);
    stageAhalf(0, 0, 0);  stageAhalf(0, 1, 0);
    stageBhalf(1, 0, 64); stageBhalf(1, 1, 64);
    stageAhalf(1, 0, 64); stageAhalf(1, 1, 64);
    asm volatile("s_waitcnt vmcnt(8)" ::: "memory");   // dbuf0 ready, dbuf1 in flight
    FENCE; __builtin_amdgcn_s_barrier(); FENCE;

    // ---- main loop: 8 iterations x 2 K-tiles ----
    for (int it = 0; it < 8; ++it) {
        const bool more = (it < 7);
        const int ka2 = it * 128 + 128, kb2 = ka2 + 64;
        bf16x8 aX[4][2], aY[4][2], bX[2][2], bY[2][2];

        rdA4(aX, Aha, 0); rdB2(bX, Bha, 0);
        asm volatile("s_waitcnt lgkmcnt(8)" ::: "memory");
        BAR_OPEN(); mfma16(aX, bX, 0, 0); BAR_CLOSE();

        rdB2(bY, Bha, 1);
        BAR_OPEN(); mfma16(aX, bY, 0, 1); BAR_CLOSE();

        rdA4(aY, Aha, 1);
        if (more) stageBhalf(0, 0, ka2);
        BAR_OPEN(); mfma16(aY, bY, 1, 1); BAR_CLOSE();

        if (more) stageBhalf(0, 1, ka2);
        BAR_OPEN(); mfma16(aY, bX, 1, 0);
        if (more) asm volatile("s_waitcnt vmcnt(4)" ::: "memory");
        else      asm volatile("s_waitcnt vmcnt(0)" ::: "memory");
        BAR_CLOSE();

        rdA4(aX, Ahb, 0); rdB2(bX, Bhb, 0);
        if (more) stageAhalf(0, 0, ka2);
        asm volatile("s_waitcnt lgkmcnt(8)" ::: "memory");
        BAR_OPEN(); mfma16(aX, bX, 0, 0); BAR_CLOSE();

        rdB2(bY, Bhb, 1);
        if (more) stageAhalf(0, 1, ka2);
        BAR_OPEN(); mfma16(aX, bY, 0, 1); BAR_CLOSE();

        rdA4(aY, Ahb, 1);
        if (more) { stageBhalf(1, 0, kb2); stageBhalf(1, 1, kb2); }
        BAR_OPEN(); mfma16(aY, bY, 1, 1); BAR_CLOSE();

        if (more) { stageAhalf(1, 0, kb2); stageAhalf(1, 1, kb2); }
        BAR_OPEN(); mfma16(aY, bX, 1, 0);
        if (more) {
            asm volatile("s_waitcnt vmcnt(8)" ::: "memory");
            BAR_CLOSE();
        }
    }

    // ---- epilogue: scatter Q (pre-scaled), Kt, Vtr ----
    {
        const int proj = colb >> 2;
        const float* bias = proj == 0 ? bqv : (proj == 1 ? bkv : bvv);
        const int cb = (colb & 3) * 256;
        float bias4[4];
        #pragma unroll
        for (int nf = 0; nf < 4; ++nf)
            bias4[nf] = bias[cb + wn * 64 + nf * 16 + l16];
        const float oscale = proj == 0 ? QSCALE : 1.0f;
        #pragma unroll
        for (int mf = 0; mf < 8; ++mf)
            #pragma unroll
            for (int rr = 0; rr < 4; ++rr) {
                int r = rowBase + wm * 128 + mf * 16 + quad * 4 + rr;
                int b_ = r >> 11, s_ = r & 2047;
                #pragma unroll
                for (int nf = 0; nf < 4; ++nf) {
                    int c = cb + wn * 64 + nf * 16 + l16;
                    float v = (acc[mf][nf][rr] + bias4[nf]) * oscale;
                    int h_ = c >> 6, d_ = c & 63;
                    size_t bh = (size_t)(b_ * NUM_HEADS + h_);
                    if (proj == 2)
                        Vtr[(bh * DK + d_) * SEQ + s_] = __float2bfloat16(v);
                    else {
                        bf16* dst = proj == 0 ? Q : Kt;
                        dst[(bh * SEQ + s_) * DK + d_] = __float2bfloat16(v);
                    }
                }
            }
    }
}

// ---------------------------------------------------------------------------
// GEMM tile staging via global_load_lds: 128 rows x 64 k (16 KB), unpadded
// stride 64, chunk-XOR swizzle. Each thread DMAs 4 x 16 B. (256 threads)
// ---------------------------------------------------------------------------
__device__ __forceinline__ void stage_gll128(const bf16* __restrict__ src,
                                             bf16* lds, int t, int k0)
{
    #pragma unroll
    for (int p = 0; p < 4; ++p) {
        int idx = t + p * 256;            // chunk id 0..1023
        int row = idx >> 3, cl = idx & 7;
        int cg = cl ^ (row & 7);
        gll16(src + (size_t)row * 1024 + k0 + cg * 8, lds + idx * 8);
    }
}

// ---------------------------------------------------------------------------
// Output projection (known-good m97-style 128x128, BK=64):
// out(f32) = ctx @ Wo^T + bo. grid (8,64) = 512 blocks = 2.0 exact rounds.
// ---------------------------------------------------------------------------
__global__ __launch_bounds__(256)
void gemm_out(const bf16* __restrict__ ctx, const bf16* __restrict__ Wb,
              const float* __restrict__ bo, float* __restrict__ out)
{
    __shared__ bf16 As[128 * 64];
    __shared__ bf16 Bs[128 * 64];
    const int t = threadIdx.x;
    const int wave = t >> 6, lane = t & 63;
    const int quad = lane >> 4, l16 = lane & 15;
    const int wr = wave >> 1, wc = wave & 1;
    const int colBase = blockIdx.x * 128;
    const int rowBase = blockIdx.y * 128;

    const bf16* Ablk = ctx + (size_t)rowBase * 1024;
    const bf16* Bblk = Wb + ((size_t)3 << 20) + (size_t)colBase * 1024;

    f32x4 acc[4][4];
    #pragma unroll
    for (int i = 0; i < 4; ++i)
        #pragma unroll
        for (int j = 0; j < 4; ++j) acc[i][j] = (f32x4){0.f, 0.f, 0.f, 0.f};

    for (int k0 = 0; k0 < 1024; k0 += 64) {
        stage_gll128(Ablk, As, t, k0);
        stage_gll128(Bblk, Bs, t, k0);
        __syncthreads();
        #pragma unroll
        for (int h = 0; h < 2; ++h) {
            bf16x8 af[4], bfr[4];
            #pragma unroll
            for (int i = 0; i < 4; ++i)
                af[i] = frag_ld(As, wr * 64 + i * 16 + l16, h, quad);
            #pragma unroll
            for (int j = 0; j < 4; ++j)
                bfr[j] = frag_ld(Bs, wc * 64 + j * 16 + l16, h, quad);
            #pragma unroll
            for (int i = 0; i < 4; ++i)
                #pragma unroll
                for (int j = 0; j < 4; ++j)
                    acc[i][j] = __builtin_amdgcn_mfma_f32_16x16x32_bf16(af[i], bfr[j],
                                                                        acc[i][j], 0, 0, 0);
        }
        __syncthreads();
    }

    float bias4[4];
    #pragma unroll
    for (int j = 0; j < 4; ++j)
        bias4[j] = bo[colBase + wc * 64 + j * 16 + l16];

    #pragma unroll
    for (int i = 0; i < 4; ++i)
        #pragma unroll
        for (int rr = 0; rr < 4; ++rr) {
            int r = rowBase + wr * 64 + i * 16 + quad * 4 + rr;
            #pragma unroll
            for (int j = 0; j < 4; ++j) {
                int c = colBase + wc * 64 + j * 16 + l16;
                out[(size_t)r * 1024 + c] = acc[i][j][rr] + bias4[j];
            }
        }
}

// ---------------------------------------------------------------------------
// Flash attention v3.1: 128 q-rows/block (4 waves x 32 rows), double-buffered
// K/V staging (one barrier per 64-key tile), K-frags cached in registers,
// V-frags shared across the two 16-row sub-blocks. Q pre-scaled: p=exp2(a).
// NEW vs v3: kt loop split into an unmasked main body (tiles 0..ntiles-3)
// and a 2-tile masked tail -- removes the per-element causal compare+cndmask
// from ~85% of tiles (pure code motion, identical math).
// grid = (bh=64, 16): linear id == bh (mod 8) -> all 16 q-blocks of one bh
// colocate on one XCD; per-XCD live K/V set = 8 bh * 0.5 MB = 4 MB = L2.
// qbi = 15 - blockIdx.y: heaviest q-blocks dispatch first (no long tail).
// ---------------------------------------------------------------------------
#define AS 72   // Ps stride only (regular ds ops, 2-way alias = free)

__device__ __forceinline__ void stage_attn(const bf16* __restrict__ Kb,
                                           const bf16* __restrict__ Vb,
                                           int k0, bf16* ks, bf16* vs, int t)
{
    #pragma unroll
    for (int p = 0; p < 2; ++p) {
        int idx = t + p * 256;            // chunk id 0..511
        int row = idx >> 3, cl = idx & 7;
        int cg = cl ^ (row & 7);
        gll16(Kb + (size_t)(k0 + row) * DK + cg * 8, ks + idx * 8);
        gll16(Vb + (size_t)row * SEQ + k0 + cg * 8, vs + idx * 8);
    }
}

__global__ __launch_bounds__(256)
void attn_mfma(const bf16* __restrict__ Q, const bf16* __restrict__ K,
               const bf16* __restrict__ Vt, bf16* __restrict__ ctx)
{
    __shared__ bf16 Ks[2][64 * 64];
    __shared__ bf16 Vs[2][64 * 64];
    __shared__ bf16 Ps[4][2][16 * AS];

    const int t    = threadIdx.x;
    const int wave = t >> 6, lane = t & 63;
    const int quad = lane >> 4, l16 = lane & 15;
    const int bh   = blockIdx.x;              // 0..63 (fast dim -> XCD = bh&7)
    const int qbi  = 15 - blockIdx.y;         // heavy blocks first
    const int b_ = bh >> 4, h_ = bh & 15;

    const bf16* Qb = Q  + (size_t)bh * SEQ * DK;
    const bf16* Kb = K  + (size_t)bh * SEQ * DK;
    const bf16* Vb = Vt + (size_t)bh * DK * SEQ;

    const int qb  = qbi * 128;
    const int ntiles = 2 * qbi + 2;               // 64-key tiles (even)

    // Q fragments for this wave's 32 rows (2 x 16-row frags, 2 k-halves)
    bf16x8 qf[2][2];
    #pragma unroll
    for (int i = 0; i < 2; ++i) {
        const int qrow = qb + wave * 32 + i * 16 + l16;
        qf[i][0] = *(const bf16x8*)(Qb + (size_t)qrow * DK + quad * 8);
        qf[i][1] = *(const bf16x8*)(Qb + (size_t)qrow * DK + 32 + quad * 8);
    }

    f32x4 O[2][4];
    float lsum[2][4];
    #pragma unroll
    for (int i = 0; i < 2; ++i)
        #pragma unroll
        for (int nc = 0; nc < 4; ++nc) {
            O[i][nc] = (f32x4){0.f, 0.f, 0.f, 0.f};
            lsum[i][nc] = 0.f;
        }

    stage_attn(Kb, Vb, 0, Ks[0], Vs[0], t);
    __syncthreads();

    int kt = 0;

    // ======== main tiles: strictly below the diagonal, no masking ========
    for (; kt < ntiles - 2; ++kt) {
        const int cur = kt & 1;
        stage_attn(Kb, Vb, kt * 64 + 64, Ks[cur ^ 1], Vs[cur ^ 1], t);

        bf16x8 kf[4][2];
        #pragma unroll
        for (int h = 0; h < 4; ++h) {
            kf[h][0] = frag_ld(Ks[cur], h * 16 + l16, 0, quad);
            kf[h][1] = frag_ld(Ks[cur], h * 16 + l16, 1, quad);
        }

        #pragma unroll
        for (int i = 0; i < 2; ++i) {
            float lacc[4];
            #pragma unroll
            for (int r = 0; r < 4; ++r) lacc[r] = lsum[i][r];
            #pragma unroll
            for (int h = 0; h < 4; ++h) {
                f32x4 a = (f32x4){0.f, 0.f, 0.f, 0.f};
                a = __builtin_amdgcn_mfma_f32_16x16x32_bf16(qf[i][0], kf[h][0], a, 0, 0, 0);
                a = __builtin_amdgcn_mfma_f32_16x16x32_bf16(qf[i][1], kf[h][1], a, 0, 0, 0);
                #pragma unroll
                for (int r = 0; r < 4; ++r) {
                    float p = exp2f(a[r]);
                    lacc[r] += p;
                    Ps[wave][i][(quad * 4 + r) * AS + h * 16 + l16] = __float2bfloat16(p);
                }
            }
            #pragma unroll
            for (int r = 0; r < 4; ++r) lsum[i][r] = lacc[r];
        }

        bf16x8 pf[2][2];
        #pragma unroll
        for (int i = 0; i < 2; ++i) {
            pf[i][0] = *(const bf16x8*)(&Ps[wave][i][l16 * AS + quad * 8]);
            pf[i][1] = *(const bf16x8*)(&Ps[wave][i][l16 * AS + 32 + quad * 8]);
        }
        __builtin_amdgcn_s_setprio(1);
        #pragma unroll
        for (int nc = 0; nc < 4; ++nc) {
            bf16x8 vf0 = frag_ld(Vs[cur], nc * 16 + l16, 0, quad);
            bf16x8 vf1 = frag_ld(Vs[cur], nc * 16 + l16, 1, quad);
            #pragma unroll
            for (int i = 0; i < 2; ++i) {
                O[i][nc] = __builtin_amdgcn_mfma_f32_16x16x32_bf16(pf[i][0], vf0, O[i][nc], 0, 0, 0);
                O[i][nc] = __builtin_amdgcn_mfma_f32_16x16x32_bf16(pf[i][1], vf1, O[i][nc], 0, 0, 0);
            }
        }
        __builtin_amdgcn_s_setprio(0);
        __syncthreads();
    }

    // ======== diagonal tail: last two tiles, causal masking ========
    for (; kt < ntiles; ++kt) {
        const int cur = kt & 1;
        const int k0  = kt * 64;
        if (kt + 1 < ntiles)
            stage_attn(Kb, Vb, k0 + 64, Ks[cur ^ 1], Vs[cur ^ 1], t);

        const bool skip = (kt == ntiles - 1) && (wave < 2);  // fully masked

        if (!skip) {
            bf16x8 kf[4][2];
            #pragma unroll
            for (int h = 0; h < 4; ++h) {
                kf[h][0] = frag_ld(Ks[cur], h * 16 + l16, 0, quad);
                kf[h][1] = frag_ld(Ks[cur], h * 16 + l16, 1, quad);
            }

            #pragma unroll
            for (int i = 0; i < 2; ++i) {
                const int qrow0i = qb + wave * 32 + i * 16;
                float lacc[4];
                #pragma unroll
                for (int r = 0; r < 4; ++r) lacc[r] = lsum[i][r];
                #pragma unroll
                for (int h = 0; h < 4; ++h) {
                    f32x4 a = (f32x4){0.f, 0.f, 0.f, 0.f};
                    a = __builtin_amdgcn_mfma_f32_16x16x32_bf16(qf[i][0], kf[h][0], a, 0, 0, 0);
                    a = __builtin_amdgcn_mfma_f32_16x16x32_bf16(qf[i][1], kf[h][1], a, 0, 0, 0);
                    #pragma unroll
                    for (int r = 0; r < 4; ++r) {
                        float ss = a[r];
                        if (k0 + h * 16 + l16 > qrow0i + quad * 4 + r)
                            ss = -1e30f;
                        float p = exp2f(ss);
                        lacc[r] += p;
                        Ps[wave][i][(quad * 4 + r) * AS + h * 16 + l16] =
                            __float2bfloat16(p);
                    }
                }
                #pragma unroll
                for (int r = 0; r < 4; ++r) lsum[i][r] = lacc[r];
            }

            bf16x8 pf[2][2];
            #pragma unroll
            for (int i = 0; i < 2; ++i) {
                pf[i][0] = *(const bf16x8*)(&Ps[wave][i][l16 * AS + quad * 8]);
                pf[i][1] = *(const bf16x8*)(&Ps[wave][i][l16 * AS + 32 + quad * 8]);
            }
            __builtin_amdgcn_s_setprio(1);
            #pragma unroll
            for (int nc = 0; nc < 4; ++nc) {
                bf16x8 vf0 = frag_ld(Vs[cur], nc * 16 + l16, 0, quad);
                bf16x8 vf1 = frag_ld(Vs[cur], nc * 16 + l16, 1, quad);
                #pragma unroll
                for (int i = 0; i < 2; ++i) {
                    O[i][nc] = __builtin_amdgcn_mfma_f32_16x16x32_bf16(pf[i][0], vf0, O[i][nc], 0, 0, 0);
                    O[i][nc] = __builtin_amdgcn_mfma_f32_16x16x32_bf16(pf[i][1], vf1, O[i][nc], 0, 0, 0);
                }
            }
            __builtin_amdgcn_s_setprio(0);
        }
        __syncthreads();
    }

    // ---- epilogue: reduce l across the 16 column-lanes, write ctx ----
    // (rcp instead of full-precision divides; bf16 output hides the ulp)
    #pragma unroll
    for (int i = 0; i < 2; ++i) {
        float inv[4];
        #pragma unroll
        for (int r = 0; r < 4; ++r) {
            #pragma unroll
            for (int off = 1; off < 16; off <<= 1)
                lsum[i][r] += __shfl_xor(lsum[i][r], off, 64);
            inv[r] = __builtin_amdgcn_rcpf(lsum[i][r]);
        }
        #pragma unroll
        for (int nc = 0; nc < 4; ++nc)
            #pragma unroll
            for (int r = 0; r < 4; ++r) {
                const int row = qb + wave * 32 + i * 16 + quad * 4 + r;
                float v = O[i][nc][r] * inv[r];
                ctx[((size_t)(b_ * SEQ + row)) * D_MODEL + h_ * DK + nc * 16 + l16] =
                    __float2bfloat16(v);
            }
    }
}

extern "C" void kernel_launch(void* const* d_in, const int* in_sizes, int n_in,
                              void* d_out, int out_size, void* d_ws, size_t ws_size,
                              hipStream_t stream) {
    const float* x  = (const float*)d_in[0];
    // d_in[1] = mask (int32) — unused; causal j<=q is exactly equivalent
    const float* Wq = (const float*)d_in[2];
    const float* bq = (const float*)d_in[3];
    const float* Wk = (const float*)d_in[4];
    const float* bk = (const float*)d_in[5];
    const float* Wv = (const float*)d_in[6];
    const float* bv = (const float*)d_in[7];
    const float* Wo = (const float*)d_in[8];
    const float* bo = (const float*)d_in[9];
    float* out = (float*)d_out;

    const size_t per = (size_t)BATCH * NUM_HEADS * SEQ * DK;  // 8388608
    bf16* Q   = (bf16*)d_ws;
    bf16* Kt  = Q  + per;
    bf16* Vtr = Kt + per;              // transposed V: [B,H,DK,S]
    bf16* xb  = Vtr + per;             // x in bf16; dead after gemm_qkv
    bf16* ctx = xb;                    // ctx aliases xb (written by attn)
    bf16* Wb  = xb + per;              // 4 x 1048576 bf16 weights (Wq,Wk,Wv,Wo)

    hipLaunchKernelGGL(cvt_bf16, dim3(12288), dim3(256), 0, stream,
                       x, Wq, Wk, Wv, Wo, xb, Wb);

    hipLaunchKernelGGL(gemm_qkv, dim3(12, 32), dim3(512), 0, stream,
                       xb, Wb, bq, bk, bv, Q, Kt, Vtr);

    hipLaunchKernelGGL(attn_mfma, dim3(64, 16), dim3(256), 0,
                       stream, Q, Kt, Vtr, ctx);

    hipLaunchKernelGGL(gemm_out, dim3(8, 64), dim3(256), 0, stream,
                       ctx, Wb, bo, out);
}